// Round 6
// baseline (97.289 us; speedup 1.0000x reference)
//
#include <hip/hip_runtime.h>
#include <hip/hip_bf16.h>
#include <math.h>

#define NS 256
#define T_LEN 8192
#define NF 32000
#define L_CH 16
#define B_BN 16
#define S_TOT 32          // B_BN + L_CH
#define C_CH 512          // T_LEN / L_CH
#define G_CH 16           // chains per block
#define NBLK 32           // C_CH / G_CH
#define SCALE 32768.0f
#define XPAD 272          // shorts per x-row (544 B): (2cj+rq)%8 uniform -> optimal b128

typedef short short8 __attribute__((ext_vector_type(8)));
typedef float f32x4 __attribute__((ext_vector_type(4)));

__device__ __forceinline__ short f2bs(float f) {
    union { __bf16 b; short s; } u; u.b = (__bf16)f; return u.s;
}
__device__ __forceinline__ float bs2f(short s) {
    union { short s; __bf16 b; } u; u.s = s; return (float)u.b;
}

// ---- combined prep: blocks [0,T_LEN) gather SE; blocks [T_LEN,+128) swizzle A
// SE[t][j] = E[j][obs[t]] * 2^15  (f32, dense rows for the chain kernel)
// Aswz frag (ntile,kk,lane,e) = bf16(A[kk*32+(lane>>4)*8+e][ntile*16+(lane&15)])
__global__ __launch_bounds__(256)
void prep(const float* __restrict__ E, const int* __restrict__ obs,
          const float* __restrict__ A,
          float* __restrict__ SE, short* __restrict__ Aswz) {
    const int b = blockIdx.x;
    if (b < T_LEN) {
        const int j = threadIdx.x;
        SE[(size_t)b * NS + j] = E[(size_t)j * NF + obs[b]] * SCALE;
    } else if (threadIdx.x < 64) {
        const int pb   = b - T_LEN;        // 0..127
        const int ntg  = pb >> 3;          // 0..15
        const int kk   = pb & 7;           // 0..7
        const int lane = threadIdx.x;
        const int col  = ntg * 16 + (lane & 15);
        const int krow = kk * 32 + (lane >> 4) * 8;
        short8 v;
#pragma unroll
        for (int e = 0; e < 8; ++e)
            v[e] = f2bs(A[(size_t)(krow + e) * NS + col]);
        *(short8*)&Aswz[((size_t)pb * 64 + lane) * 8] = v;
    }
}

// ---- chained MFMA steps: 32 blocks x 256 threads, 16 chains/block ---------
__global__ __launch_bounds__(256, 1)
void hmm_chains(const float* __restrict__ start,
                const float* __restrict__ SE,
                const short* __restrict__ Aswz,
                float* __restrict__ zbuf,
                float* __restrict__ Pb, float* __restrict__ Qb)
{
    const int bid  = blockIdx.x;
    const int tid  = threadIdx.x;
    const int w    = tid >> 6;          // wave 0..3 (N-tiles 4w..4w+3)
    const int lane = tid & 63;
    const int cj   = lane & 15;
    const int rq   = lane >> 4;
    const int base = 256 * bid - 16;    // t = base + 16*g + s

    __shared__ short xb[2][G_CH][XPAD];

    // B-fragments of A: 32 x short8 = 128 VGPRs, loaded once and PINNED
    short8 bfr[4][8];
    const short8* Av = (const short8*)Aswz;
#pragma unroll
    for (int nt = 0; nt < 4; ++nt)
#pragma unroll
        for (int kk = 0; kk < 8; ++kk)
            bfr[nt][kk] = Av[((w * 4 + nt) * 8 + kk) * 64 + lane];
#pragma unroll
    for (int nt = 0; nt < 4; ++nt)
#pragma unroll
        for (int kk = 0; kk < 8; ++kk)
            asm volatile("" : "+v"(bfr[nt][kk]));   // opaque: no remat, no reload

    // burn-in start: x = 1
    for (int idx = tid; idx < G_CH * XPAD; idx += 256)
        ((short*)xb[0])[idx] = f2bs(1.0f);

    int cols[4];
#pragma unroll
    for (int nt = 0; nt < 4; ++nt) cols[nt] = (w * 4 + nt) * 16 + cj;

    // prologue: emissions for s = 1
    float evc[4][4], evn[4][4];
#pragma unroll
    for (int r = 0; r < 4; ++r) {
        int t = base + 16 * (rq * 4 + r) + 1;
        t = t < 0 ? 0 : t;
#pragma unroll
        for (int nt = 0; nt < 4; ++nt)
            evc[nt][r] = SE[(size_t)t * NS + cols[nt]];
    }

    for (int s = 1; s < S_TOT; ++s) {
        __syncthreads();
        const int rb = (s - 1) & 1, wb = s & 1;

        if (s == B_BN) {   // Q stitch: burned-in state at t = base+16g+15
            int g = tid >> 4, part = tid & 15;
            float ss = 0.f;
            const short* row = &xb[rb][g][part * 16];
#pragma unroll
            for (int i = 0; i < 16; ++i) ss += bs2f(row[i]);
#pragma unroll
            for (int m = 1; m < 16; m <<= 1) ss += __shfl_xor(ss, m, 16);
            if (part == 0) {
                int t1 = base + 16 * g + 16;
                Qb[bid * G_CH + g] = log2f(ss) - 15.0f * (float)t1;
            }
        }

        // prefetch emissions for s+1 (dense SE rows, no obs indirection)
#pragma unroll
        for (int r = 0; r < 4; ++r) {
            int t = base + 16 * (rq * 4 + r) + s + 1;
            t = t < 0 ? 0 : (t > T_LEN - 1 ? T_LEN - 1 : t);
#pragma unroll
            for (int nt = 0; nt < 4; ++nt)
                evn[nt][r] = SE[(size_t)t * NS + cols[nt]];
        }

        // x A-frags: lane holds x[m=cj][k = kk*32 + rq*8 + 0..7]
        short8 ax[8];
#pragma unroll
        for (int kk = 0; kk < 8; ++kk)
            ax[kk] = *(const short8*)&xb[rb][cj][kk * 32 + rq * 8];

        f32x4 acc[4];
#pragma unroll
        for (int nt = 0; nt < 4; ++nt) {
            acc[nt] = (f32x4){0.f, 0.f, 0.f, 0.f};
#pragma unroll
            for (int kk = 0; kk < 8; ++kk)
                acc[nt] = __builtin_amdgcn_mfma_f32_16x16x32_bf16(
                    ax[kk], bfr[nt][kk], acc[nt], 0, 0, 0);
        }

        const bool body = (s >= B_BN);
#pragma unroll
        for (int nt = 0; nt < 4; ++nt) {
#pragma unroll
            for (int r = 0; r < 4; ++r) {
                int g = rq * 4 + r;
                float y = acc[nt][r] * evc[nt][r];
                bool skip = (bid == 0) && (s == B_BN) && (g == 0);
                if (!skip) {
                    xb[wb][g][cols[nt]] = f2bs(y);
                    if (body) {
                        int tg = base + 16 * g + s;
                        zbuf[(size_t)tg * NS + cols[nt]] = y;
                    }
                }
            }
        }

        // chain 0 exact re-init at s == B (t = 0)
        if (bid == 0 && s == B_BN) {
            float y0 = start[tid] * SE[tid];
            xb[wb][0][tid] = f2bs(y0);
            zbuf[tid] = y0;
        }

#pragma unroll
        for (int nt = 0; nt < 4; ++nt)
#pragma unroll
            for (int r = 0; r < 4; ++r) evc[nt][r] = evn[nt][r];
    }

    // P stitch: chunk-end state at t = base+16g+31, from xb[1]
    __syncthreads();
    {
        int g = tid >> 4, part = tid & 15;
        float ss = 0.f;
        const short* row = &xb[1][g][part * 16];
#pragma unroll
        for (int i = 0; i < 16; ++i) ss += bs2f(row[i]);
#pragma unroll
        for (int m = 1; m < 16; m <<= 1) ss += __shfl_xor(ss, m, 16);
        if (part == 0) {
            int t1 = base + 16 * g + 32;
            Pb[bid * G_CH + g] = log2f(ss) - 15.0f * (float)t1;
        }
    }
}

// ---- stitch: parallel f64 Kogge-Stone scan over 512 chunk offsets ---------
__global__ __launch_bounds__(512)
void hmm_stitch(const float* __restrict__ Pb,
                const float* __restrict__ Qb,
                float* __restrict__ Dfull)
{
    __shared__ double x[C_CH];
    const int i = threadIdx.x;
    x[i] = (i == 0) ? 0.0 : ((double)Pb[i - 1] - (double)Qb[i]);
    __syncthreads();
    for (int ofs = 1; ofs < C_CH; ofs <<= 1) {
        double v = (i >= ofs) ? x[i - ofs] : 0.0;
        __syncthreads();
        x[i] += v;
        __syncthreads();
    }
    for (int t = i; t < T_LEN; t += 512)
        Dfull[t] = (float)(x[t >> 4] - 15.0 * (double)(t + 1));
}

// ---- finalize: log2 + offset, 64x64 tiled transpose to [NS][T] ------------
__global__ __launch_bounds__(256)
void hmm_finalize(const float* __restrict__ zbuf,
                  const float* __restrict__ Dfull,
                  float* __restrict__ out)
{
    __shared__ float tile[64][65];
    const int t0   = blockIdx.x * 64;
    const int j0   = blockIdx.y * 64;
    const int lane = threadIdx.x & 63;
    const int row4 = threadIdx.x >> 6;
    const float LN2 = 0.69314718055994530942f;

#pragma unroll
    for (int r = 0; r < 16; ++r) {
        int trow = r * 4 + row4;
        int t = t0 + trow;
        float z = zbuf[(size_t)t * NS + j0 + lane];
        tile[trow][lane] = __log2f(z) + Dfull[t];
    }
    __syncthreads();
#pragma unroll
    for (int r = 0; r < 16; ++r) {
        int jrow = r * 4 + row4;
        out[(size_t)(j0 + jrow) * T_LEN + t0 + lane] = LN2 * tile[lane][jrow];
    }
}

// ---- fallback: single-workgroup sequential --------------------------------
__global__ __launch_bounds__(NS, 1)
void hmm_forward_seq(const float* __restrict__ start,
                     const float* __restrict__ A,
                     const float* __restrict__ E,
                     const int* __restrict__ obs,
                     float* __restrict__ out)
{
    __shared__ float xbuf[2][NS];
    __shared__ float red[4];
    const int j = threadIdx.x;
    float a[NS];
#pragma unroll
    for (int i = 0; i < NS; ++i) a[i] = A[i * NS + j];
    const float LN2 = 0.69314718055994530942f;
    float Eacc = 0.0f;
    float z = start[j] * E[(size_t)j * NF + obs[0]] * SCALE;
    out[(size_t)j * T_LEN + 0] = LN2 * (__log2f(z) - 15.0f);
    xbuf[0][j] = z;
    __syncthreads();
    float se_cur = E[(size_t)j * NF + obs[1]] * SCALE;
    for (int t = 1; t < T_LEN; ++t) {
        float se_nxt = 0.0f;
        if (t + 1 < T_LEN) se_nxt = E[(size_t)j * NF + obs[t + 1]] * SCALE;
        const float4* x4 = (const float4*)xbuf[(t - 1) & 1];
        float y0 = 0.f, y1 = 0.f, y2 = 0.f, y3 = 0.f;
#pragma unroll
        for (int i = 0; i < NS / 4; ++i) {
            float4 xv = x4[i];
            y0 = fmaf(xv.x, a[4 * i + 0], y0);
            y1 = fmaf(xv.y, a[4 * i + 1], y1);
            y2 = fmaf(xv.z, a[4 * i + 2], y2);
            y3 = fmaf(xv.w, a[4 * i + 3], y3);
        }
        float y = ((y0 + y1) + (y2 + y3)) * se_cur;
        se_cur = se_nxt;
        out[(size_t)j * T_LEN + t] =
            LN2 * (__log2f(y) + Eacc - 15.0f * (float)(t + 1));
        float* wr = xbuf[t & 1];
        wr[j] = y;
        __syncthreads();
        if ((t & 1023) == 1023) {
            float v = wr[j];
#pragma unroll
            for (int d = 1; d < 64; d <<= 1) v = fmaxf(v, __shfl_xor(v, d, 64));
            if ((j & 63) == 0) red[j >> 6] = v;
            __syncthreads();
            float m = fmaxf(fmaxf(red[0], red[1]), fmaxf(red[2], red[3]));
            int k = ilogbf(m);
            wr[j] = ldexpf(wr[j], -k);
            Eacc += (float)k;
            __syncthreads();
        }
    }
}

extern "C" void kernel_launch(void* const* d_in, const int* in_sizes, int n_in,
                              void* d_out, int out_size, void* d_ws, size_t ws_size,
                              hipStream_t stream) {
    const float* start = (const float*)d_in[0];
    const float* A     = (const float*)d_in[1];
    const float* E     = (const float*)d_in[2];
    const int*   obs   = (const int*)d_in[3];
    float* out = (float*)d_out;

    char* ws = (char*)d_ws;
    const size_t zb_bytes  = (size_t)T_LEN * NS * sizeof(float);      // 8 MB
    const size_t se_bytes  = (size_t)T_LEN * NS * sizeof(float);      // 8 MB
    const size_t asw_bytes = (size_t)128 * 64 * 8 * sizeof(short);    // 128 KB

    float* z     = (float*)ws;
    float* SE    = (float*)(ws + zb_bytes);
    short* Aswz  = (short*)(ws + zb_bytes + se_bytes);
    float* Pb    = (float*)(ws + zb_bytes + se_bytes + asw_bytes);
    float* Qb    = Pb + C_CH;
    float* Dfull = Qb + C_CH;

    const size_t need = zb_bytes + se_bytes + asw_bytes +
                        (2 * C_CH + T_LEN) * sizeof(float);

    if (ws_size >= need) {
        prep<<<T_LEN + 128, 256, 0, stream>>>(E, obs, A, SE, Aswz);
        hmm_chains<<<NBLK, 256, 0, stream>>>(start, SE, Aswz, z, Pb, Qb);
        hmm_stitch<<<1, 512, 0, stream>>>(Pb, Qb, Dfull);
        hmm_finalize<<<dim3(T_LEN / 64, NS / 64), 256, 0, stream>>>(z, Dfull, out);
    } else {
        hmm_forward_seq<<<1, NS, 0, stream>>>(start, A, E, obs, out);
    }
}

// Round 7
// 84.055 us; speedup vs baseline: 1.1574x; 1.1574x over previous
//
#include <hip/hip_runtime.h>
#include <hip/hip_bf16.h>
#include <math.h>

#define NS 256
#define T_LEN 8192
#define NF 32000
#define L_CH 8
#define B_BN 16
#define S_TOT 24          // B_BN + L_CH
#define C_CH 1024         // T_LEN / L_CH
#define G_CH 16           // chains per block
#define NBLK 64           // C_CH / G_CH
#define SCALE 32768.0f
#define XPAD 272          // shorts per x-row (544 B)

typedef short short8 __attribute__((ext_vector_type(8)));
typedef float f32x4 __attribute__((ext_vector_type(4)));

__device__ __forceinline__ short f2bs(float f) {
    union { __bf16 b; short s; } u; u.b = (__bf16)f; return u.s;
}
__device__ __forceinline__ float bs2f(short s) {
    union { short s; __bf16 b; } u; u.s = s; return (float)u.b;
}

// LDS-only barrier: drain own LDS ops, sync, but let global loads/stores ride.
__device__ __forceinline__ void sync_lds_only() {
    __builtin_amdgcn_sched_barrier(0);
    asm volatile("s_waitcnt lgkmcnt(0)" ::: "memory");
    __builtin_amdgcn_s_barrier();
    __builtin_amdgcn_sched_barrier(0);
}

// ---- combined prep: blocks [0,T_LEN) gather SE; blocks [T_LEN,+128) swizzle A
__global__ __launch_bounds__(256)
void prep(const float* __restrict__ E, const int* __restrict__ obs,
          const float* __restrict__ A,
          float* __restrict__ SE, short* __restrict__ Aswz) {
    const int b = blockIdx.x;
    if (b < T_LEN) {
        const int j = threadIdx.x;
        SE[(size_t)b * NS + j] = E[(size_t)j * NF + obs[b]] * SCALE;
    } else if (threadIdx.x < 64) {
        const int pb   = b - T_LEN;        // 0..127
        const int ntg  = pb >> 3;          // 0..15
        const int kk   = pb & 7;           // 0..7
        const int lane = threadIdx.x;
        const int col  = ntg * 16 + (lane & 15);
        const int krow = kk * 32 + (lane >> 4) * 8;
        short8 v;
#pragma unroll
        for (int e = 0; e < 8; ++e)
            v[e] = f2bs(A[(size_t)(krow + e) * NS + col]);
        *(short8*)&Aswz[((size_t)pb * 64 + lane) * 8] = v;
    }
}

// ---- chained MFMA steps: 64 blocks x 256 threads, 16 chains/block ---------
__global__ __launch_bounds__(256, 1)
void hmm_chains(const float* __restrict__ start,
                const float* __restrict__ SE,
                const short* __restrict__ Aswz,
                float* __restrict__ zbuf,
                float* __restrict__ Pb, float* __restrict__ Qb)
{
    const int bid  = blockIdx.x;
    const int tid  = threadIdx.x;
    const int w    = tid >> 6;          // wave 0..3 (N-tiles 4w..4w+3)
    const int lane = tid & 63;
    const int cj   = lane & 15;
    const int rq   = lane >> 4;
    const int base = 128 * bid - 16;    // t = base + 8*g + s

    __shared__ short xb[2][G_CH][XPAD];

    // B-fragments of A: 32 x short8 = 128 VGPRs, loaded once and pinned
    short8 bfr[4][8];
    const short8* Av = (const short8*)Aswz;
#pragma unroll
    for (int nt = 0; nt < 4; ++nt)
#pragma unroll
        for (int kk = 0; kk < 8; ++kk)
            bfr[nt][kk] = Av[((w * 4 + nt) * 8 + kk) * 64 + lane];
#pragma unroll
    for (int nt = 0; nt < 4; ++nt)
#pragma unroll
        for (int kk = 0; kk < 8; ++kk)
            asm volatile("" : "+v"(bfr[nt][kk]));

    // burn-in start: x = 1
    for (int idx = tid; idx < G_CH * XPAD; idx += 256)
        ((short*)xb[0])[idx] = f2bs(1.0f);

    int cols[4];
#pragma unroll
    for (int nt = 0; nt < 4; ++nt) cols[nt] = (w * 4 + nt) * 16 + cj;

    // prologue: emissions for s = 1
    float evc[4][4], evn[4][4];
#pragma unroll
    for (int r = 0; r < 4; ++r) {
        int t = base + 8 * (rq * 4 + r) + 1;
        t = t < 0 ? 0 : t;
#pragma unroll
        for (int nt = 0; nt < 4; ++nt)
            evc[nt][r] = SE[(size_t)t * NS + cols[nt]];
    }

    for (int s = 1; s < S_TOT; ++s) {
        sync_lds_only();
        const int rb = (s - 1) & 1, wb = s & 1;

        if (s == B_BN) {   // Q stitch: burned-in state at t = base+8g+15
            int g = tid >> 4, part = tid & 15;
            float ss = 0.f;
            const short* row = &xb[rb][g][part * 16];
#pragma unroll
            for (int i = 0; i < 16; ++i) ss += bs2f(row[i]);
#pragma unroll
            for (int m = 1; m < 16; m <<= 1) ss += __shfl_xor(ss, m, 16);
            if (part == 0) {
                int t1 = base + 8 * g + 16;
                Qb[bid * G_CH + g] = log2f(ss) - 15.0f * (float)t1;
            }
        }

        // prefetch emissions for s+1 (dense SE rows)
#pragma unroll
        for (int r = 0; r < 4; ++r) {
            int t = base + 8 * (rq * 4 + r) + s + 1;
            t = t < 0 ? 0 : (t > T_LEN - 1 ? T_LEN - 1 : t);
#pragma unroll
            for (int nt = 0; nt < 4; ++nt)
                evn[nt][r] = SE[(size_t)t * NS + cols[nt]];
        }

        // x A-frags: lane holds x[m=cj][k = kk*32 + rq*8 + 0..7]
        short8 ax[8];
#pragma unroll
        for (int kk = 0; kk < 8; ++kk)
            ax[kk] = *(const short8*)&xb[rb][cj][kk * 32 + rq * 8];

        f32x4 acc[4];
#pragma unroll
        for (int nt = 0; nt < 4; ++nt) {
            acc[nt] = (f32x4){0.f, 0.f, 0.f, 0.f};
#pragma unroll
            for (int kk = 0; kk < 8; ++kk)
                acc[nt] = __builtin_amdgcn_mfma_f32_16x16x32_bf16(
                    ax[kk], bfr[nt][kk], acc[nt], 0, 0, 0);
        }

        const bool body = (s >= B_BN);
#pragma unroll
        for (int nt = 0; nt < 4; ++nt) {
#pragma unroll
            for (int r = 0; r < 4; ++r) {
                int g = rq * 4 + r;
                float y = acc[nt][r] * evc[nt][r];
                bool skip = (bid == 0) && (s == B_BN) && (g == 0);
                if (!skip) {
                    xb[wb][g][cols[nt]] = f2bs(y);
                    if (body) {
                        int tg = base + 8 * g + s;
                        zbuf[(size_t)tg * NS + cols[nt]] = y;
                    }
                }
            }
        }

        // chain 0 exact re-init at s == B (t = 0)
        if (bid == 0 && s == B_BN) {
            float y0 = start[tid] * SE[tid];
            xb[wb][0][tid] = f2bs(y0);
            zbuf[tid] = y0;
        }

#pragma unroll
        for (int nt = 0; nt < 4; ++nt)
#pragma unroll
            for (int r = 0; r < 4; ++r) evc[nt][r] = evn[nt][r];
    }

    // P stitch: chunk-end state at t = base+8g+23, from xb[1]
    sync_lds_only();
    {
        int g = tid >> 4, part = tid & 15;
        float ss = 0.f;
        const short* row = &xb[1][g][part * 16];
#pragma unroll
        for (int i = 0; i < 16; ++i) ss += bs2f(row[i]);
#pragma unroll
        for (int m = 1; m < 16; m <<= 1) ss += __shfl_xor(ss, m, 16);
        if (part == 0) {
            int t1 = base + 8 * g + 24;
            Pb[bid * G_CH + g] = log2f(ss) - 15.0f * (float)t1;
        }
    }
}

// ---- stitch: parallel f64 Kogge-Stone scan over 1024 chunk offsets --------
__global__ __launch_bounds__(1024)
void hmm_stitch(const float* __restrict__ Pb,
                const float* __restrict__ Qb,
                float* __restrict__ Dfull)
{
    __shared__ double x[C_CH];
    const int i = threadIdx.x;
    x[i] = (i == 0) ? 0.0 : ((double)Pb[i - 1] - (double)Qb[i]);
    __syncthreads();
    for (int ofs = 1; ofs < C_CH; ofs <<= 1) {
        double v = (i >= ofs) ? x[i - ofs] : 0.0;
        __syncthreads();
        x[i] += v;
        __syncthreads();
    }
    for (int t = i; t < T_LEN; t += 1024)
        Dfull[t] = (float)(x[t >> 3] - 15.0 * (double)(t + 1));
}

// ---- finalize: log2 + offset, 64x64 tiled transpose to [NS][T] ------------
__global__ __launch_bounds__(256)
void hmm_finalize(const float* __restrict__ zbuf,
                  const float* __restrict__ Dfull,
                  float* __restrict__ out)
{
    __shared__ float tile[64][65];
    const int t0   = blockIdx.x * 64;
    const int j0   = blockIdx.y * 64;
    const int lane = threadIdx.x & 63;
    const int row4 = threadIdx.x >> 6;
    const float LN2 = 0.69314718055994530942f;

#pragma unroll
    for (int r = 0; r < 16; ++r) {
        int trow = r * 4 + row4;
        int t = t0 + trow;
        float z = zbuf[(size_t)t * NS + j0 + lane];
        tile[trow][lane] = __log2f(z) + Dfull[t];
    }
    __syncthreads();
#pragma unroll
    for (int r = 0; r < 16; ++r) {
        int jrow = r * 4 + row4;
        out[(size_t)(j0 + jrow) * T_LEN + t0 + lane] = LN2 * tile[lane][jrow];
    }
}

// ---- fallback: single-workgroup sequential --------------------------------
__global__ __launch_bounds__(NS, 1)
void hmm_forward_seq(const float* __restrict__ start,
                     const float* __restrict__ A,
                     const float* __restrict__ E,
                     const int* __restrict__ obs,
                     float* __restrict__ out)
{
    __shared__ float xbuf[2][NS];
    __shared__ float red[4];
    const int j = threadIdx.x;
    float a[NS];
#pragma unroll
    for (int i = 0; i < NS; ++i) a[i] = A[i * NS + j];
    const float LN2 = 0.69314718055994530942f;
    float Eacc = 0.0f;
    float z = start[j] * E[(size_t)j * NF + obs[0]] * SCALE;
    out[(size_t)j * T_LEN + 0] = LN2 * (__log2f(z) - 15.0f);
    xbuf[0][j] = z;
    __syncthreads();
    float se_cur = E[(size_t)j * NF + obs[1]] * SCALE;
    for (int t = 1; t < T_LEN; ++t) {
        float se_nxt = 0.0f;
        if (t + 1 < T_LEN) se_nxt = E[(size_t)j * NF + obs[t + 1]] * SCALE;
        const float4* x4 = (const float4*)xbuf[(t - 1) & 1];
        float y0 = 0.f, y1 = 0.f, y2 = 0.f, y3 = 0.f;
#pragma unroll
        for (int i = 0; i < NS / 4; ++i) {
            float4 xv = x4[i];
            y0 = fmaf(xv.x, a[4 * i + 0], y0);
            y1 = fmaf(xv.y, a[4 * i + 1], y1);
            y2 = fmaf(xv.z, a[4 * i + 2], y2);
            y3 = fmaf(xv.w, a[4 * i + 3], y3);
        }
        float y = ((y0 + y1) + (y2 + y3)) * se_cur;
        se_cur = se_nxt;
        out[(size_t)j * T_LEN + t] =
            LN2 * (__log2f(y) + Eacc - 15.0f * (float)(t + 1));
        float* wr = xbuf[t & 1];
        wr[j] = y;
        __syncthreads();
        if ((t & 1023) == 1023) {
            float v = wr[j];
#pragma unroll
            for (int d = 1; d < 64; d <<= 1) v = fmaxf(v, __shfl_xor(v, d, 64));
            if ((j & 63) == 0) red[j >> 6] = v;
            __syncthreads();
            float m = fmaxf(fmaxf(red[0], red[1]), fmaxf(red[2], red[3]));
            int k = ilogbf(m);
            wr[j] = ldexpf(wr[j], -k);
            Eacc += (float)k;
            __syncthreads();
        }
    }
}

extern "C" void kernel_launch(void* const* d_in, const int* in_sizes, int n_in,
                              void* d_out, int out_size, void* d_ws, size_t ws_size,
                              hipStream_t stream) {
    const float* start = (const float*)d_in[0];
    const float* A     = (const float*)d_in[1];
    const float* E     = (const float*)d_in[2];
    const int*   obs   = (const int*)d_in[3];
    float* out = (float*)d_out;

    char* ws = (char*)d_ws;
    const size_t zb_bytes  = (size_t)T_LEN * NS * sizeof(float);      // 8 MB
    const size_t se_bytes  = (size_t)T_LEN * NS * sizeof(float);      // 8 MB
    const size_t asw_bytes = (size_t)128 * 64 * 8 * sizeof(short);    // 128 KB

    float* z     = (float*)ws;
    float* SE    = (float*)(ws + zb_bytes);
    short* Aswz  = (short*)(ws + zb_bytes + se_bytes);
    float* Pb    = (float*)(ws + zb_bytes + se_bytes + asw_bytes);
    float* Qb    = Pb + C_CH;
    float* Dfull = Qb + C_CH;

    const size_t need = zb_bytes + se_bytes + asw_bytes +
                        (2 * C_CH + T_LEN) * sizeof(float);

    if (ws_size >= need) {
        prep<<<T_LEN + 128, 256, 0, stream>>>(E, obs, A, SE, Aswz);
        hmm_chains<<<NBLK, 256, 0, stream>>>(start, SE, Aswz, z, Pb, Qb);
        hmm_stitch<<<1, 1024, 0, stream>>>(Pb, Qb, Dfull);
        hmm_finalize<<<dim3(T_LEN / 64, NS / 64), 256, 0, stream>>>(z, Dfull, out);
    } else {
        hmm_forward_seq<<<1, NS, 0, stream>>>(start, A, E, obs, out);
    }
}

// Round 8
// 73.588 us; speedup vs baseline: 1.3221x; 1.1422x over previous
//
#include <hip/hip_runtime.h>
#include <hip/hip_bf16.h>
#include <math.h>

#define NS 256
#define T_LEN 8192
#define NF 32000
#define L_CH 8
#define B_BN 16
#define S_TOT 24          // B_BN + L_CH
#define C_CH 1024         // T_LEN / L_CH
#define G_CH 16           // chains per block
#define NBLK 64           // C_CH / G_CH
#define SCALE 32768.0f
#define XPAD 264          // shorts per x-row (528 B = 132 dwords; 132%32=4 -> uniform b128 slots)

typedef short short8 __attribute__((ext_vector_type(8)));
typedef float f32x4 __attribute__((ext_vector_type(4)));

__device__ __forceinline__ short f2bs(float f) {
    union { __bf16 b; short s; } u; u.b = (__bf16)f; return u.s;
}
__device__ __forceinline__ float bs2f(short s) {
    union { short s; __bf16 b; } u; u.s = s; return (float)u.b;
}

// LDS-only barrier: drain own LDS ops, sync; let global loads/stores ride.
__device__ __forceinline__ void sync_lds_only() {
    __builtin_amdgcn_sched_barrier(0);
    asm volatile("s_waitcnt lgkmcnt(0)" ::: "memory");
    __builtin_amdgcn_s_barrier();
    __builtin_amdgcn_sched_barrier(0);
}

// ---- combined prep: blocks [0,T_LEN) gather SE; blocks [T_LEN,+128) swizzle A
__global__ __launch_bounds__(256)
void prep(const float* __restrict__ E, const int* __restrict__ obs,
          const float* __restrict__ A,
          float* __restrict__ SE, short* __restrict__ Aswz) {
    const int b = blockIdx.x;
    if (b < T_LEN) {
        const int j = threadIdx.x;
        SE[(size_t)b * NS + j] = E[(size_t)j * NF + obs[b]] * SCALE;
    } else if (threadIdx.x < 64) {
        const int pb   = b - T_LEN;        // 0..127
        const int ntg  = pb >> 3;          // 0..15
        const int kk   = pb & 7;           // 0..7
        const int lane = threadIdx.x;
        const int col  = ntg * 16 + (lane & 15);
        const int krow = kk * 32 + (lane >> 4) * 8;
        short8 v;
#pragma unroll
        for (int e = 0; e < 8; ++e)
            v[e] = f2bs(A[(size_t)(krow + e) * NS + col]);
        *(short8*)&Aswz[((size_t)pb * 64 + lane) * 8] = v;
    }
}

// ---- chained MFMA steps: 64 blocks x 1024 threads (16 waves), 16 chains ---
// Wave wv owns n-tile wv (cols 16wv..16wv+15): bfr = 8 x short8 = 32 VGPRs.
__global__ __launch_bounds__(1024, 4)
void hmm_chains(const float* __restrict__ start,
                const float* __restrict__ SE,
                const short* __restrict__ Aswz,
                float* __restrict__ zbuf,
                float* __restrict__ Pb, float* __restrict__ Qb)
{
    const int bid  = blockIdx.x;
    const int tid  = threadIdx.x;
    const int wv   = tid >> 6;          // wave 0..15 = n-tile
    const int lane = tid & 63;
    const int cj   = lane & 15;
    const int rq   = lane >> 4;
    const int col  = wv * 16 + cj;
    const int base = 128 * bid - 16;    // t = base + 8*g + s

    __shared__ short xb[2][G_CH][XPAD];

    // this wave's B-fragments of A: 8 x short8 = 32 VGPRs
    short8 bfr[8];
    const short8* Av = (const short8*)Aswz;
#pragma unroll
    for (int kk = 0; kk < 8; ++kk)
        bfr[kk] = Av[((size_t)(wv * 8 + kk)) * 64 + lane];
#pragma unroll
    for (int kk = 0; kk < 8; ++kk)
        asm volatile("" : "+v"(bfr[kk]));

    // burn-in start: x = 1
    for (int idx = tid; idx < G_CH * XPAD; idx += 1024)
        ((short*)xb[0])[idx] = f2bs(1.0f);

    // prologue: emissions for s = 1 (4 per lane: rows g = rq*4+r)
    float evc[4], evn[4];
#pragma unroll
    for (int r = 0; r < 4; ++r) {
        int t = base + 8 * (rq * 4 + r) + 1;
        t = t < 0 ? 0 : t;
        evc[r] = SE[(size_t)t * NS + col];
    }

    for (int s = 1; s < S_TOT; ++s) {
        sync_lds_only();
        const int rb = (s - 1) & 1, wb = s & 1;

        if (s == B_BN && tid < 256) {   // Q stitch at t = base+8g+15
            int g = tid >> 4, part = tid & 15;
            float ss = 0.f;
            const short* row = &xb[rb][g][part * 16];
#pragma unroll
            for (int i = 0; i < 16; ++i) ss += bs2f(row[i]);
#pragma unroll
            for (int m = 1; m < 16; m <<= 1) ss += __shfl_xor(ss, m, 16);
            if (part == 0) {
                int t1 = base + 8 * g + 16;
                Qb[bid * G_CH + g] = log2f(ss) - 15.0f * (float)t1;
            }
        }

        // prefetch emissions for s+1
#pragma unroll
        for (int r = 0; r < 4; ++r) {
            int t = base + 8 * (rq * 4 + r) + s + 1;
            t = t < 0 ? 0 : (t > T_LEN - 1 ? T_LEN - 1 : t);
            evn[r] = SE[(size_t)t * NS + col];
        }

        // x A-frags: lane holds x[m=cj][k = kk*32 + rq*8 + 0..7]
        short8 ax[8];
#pragma unroll
        for (int kk = 0; kk < 8; ++kk)
            ax[kk] = *(const short8*)&xb[rb][cj][kk * 32 + rq * 8];

        f32x4 acc = (f32x4){0.f, 0.f, 0.f, 0.f};
#pragma unroll
        for (int kk = 0; kk < 8; ++kk)
            acc = __builtin_amdgcn_mfma_f32_16x16x32_bf16(ax[kk], bfr[kk], acc, 0, 0, 0);

        const bool body = (s >= B_BN);
#pragma unroll
        for (int r = 0; r < 4; ++r) {
            int g = rq * 4 + r;
            float y = acc[r] * evc[r];
            bool skip = (bid == 0) && (s == B_BN) && (g == 0);
            if (!skip) {
                xb[wb][g][col] = f2bs(y);
                if (body) {
                    int tg = base + 8 * g + s;
                    zbuf[(size_t)tg * NS + col] = y;
                }
            }
        }

        // chain 0 exact re-init at s == B (t = 0)
        if (bid == 0 && s == B_BN && tid < 256) {
            float y0 = start[tid] * SE[tid];
            xb[wb][0][tid] = f2bs(y0);
            zbuf[tid] = y0;
        }

#pragma unroll
        for (int r = 0; r < 4; ++r) evc[r] = evn[r];
    }

    // P stitch: chunk-end state at t = base+8g+23, from xb[1]
    sync_lds_only();
    if (tid < 256) {
        int g = tid >> 4, part = tid & 15;
        float ss = 0.f;
        const short* row = &xb[1][g][part * 16];
#pragma unroll
        for (int i = 0; i < 16; ++i) ss += bs2f(row[i]);
#pragma unroll
        for (int m = 1; m < 16; m <<= 1) ss += __shfl_xor(ss, m, 16);
        if (part == 0) {
            int t1 = base + 8 * g + 24;
            Pb[bid * G_CH + g] = log2f(ss) - 15.0f * (float)t1;
        }
    }
}

// ---- stitch: parallel f64 Kogge-Stone scan over 1024 chunk offsets --------
__global__ __launch_bounds__(1024)
void hmm_stitch(const float* __restrict__ Pb,
                const float* __restrict__ Qb,
                float* __restrict__ Dfull)
{
    __shared__ double x[C_CH];
    const int i = threadIdx.x;
    x[i] = (i == 0) ? 0.0 : ((double)Pb[i - 1] - (double)Qb[i]);
    __syncthreads();
    for (int ofs = 1; ofs < C_CH; ofs <<= 1) {
        double v = (i >= ofs) ? x[i - ofs] : 0.0;
        __syncthreads();
        x[i] += v;
        __syncthreads();
    }
    for (int t = i; t < T_LEN; t += 1024)
        Dfull[t] = (float)(x[t >> 3] - 15.0 * (double)(t + 1));
}

// ---- finalize: log2 + offset, 64x64 tiled transpose to [NS][T] ------------
__global__ __launch_bounds__(256)
void hmm_finalize(const float* __restrict__ zbuf,
                  const float* __restrict__ Dfull,
                  float* __restrict__ out)
{
    __shared__ float tile[64][65];
    const int t0   = blockIdx.x * 64;
    const int j0   = blockIdx.y * 64;
    const int lane = threadIdx.x & 63;
    const int row4 = threadIdx.x >> 6;
    const float LN2 = 0.69314718055994530942f;

#pragma unroll
    for (int r = 0; r < 16; ++r) {
        int trow = r * 4 + row4;
        int t = t0 + trow;
        float z = zbuf[(size_t)t * NS + j0 + lane];
        tile[trow][lane] = __log2f(z) + Dfull[t];
    }
    __syncthreads();
#pragma unroll
    for (int r = 0; r < 16; ++r) {
        int jrow = r * 4 + row4;
        out[(size_t)(j0 + jrow) * T_LEN + t0 + lane] = LN2 * tile[lane][jrow];
    }
}

// ---- fallback: single-workgroup sequential --------------------------------
__global__ __launch_bounds__(NS, 1)
void hmm_forward_seq(const float* __restrict__ start,
                     const float* __restrict__ A,
                     const float* __restrict__ E,
                     const int* __restrict__ obs,
                     float* __restrict__ out)
{
    __shared__ float xbuf[2][NS];
    __shared__ float red[4];
    const int j = threadIdx.x;
    float a[NS];
#pragma unroll
    for (int i = 0; i < NS; ++i) a[i] = A[i * NS + j];
    const float LN2 = 0.69314718055994530942f;
    float Eacc = 0.0f;
    float z = start[j] * E[(size_t)j * NF + obs[0]] * SCALE;
    out[(size_t)j * T_LEN + 0] = LN2 * (__log2f(z) - 15.0f);
    xbuf[0][j] = z;
    __syncthreads();
    float se_cur = E[(size_t)j * NF + obs[1]] * SCALE;
    for (int t = 1; t < T_LEN; ++t) {
        float se_nxt = 0.0f;
        if (t + 1 < T_LEN) se_nxt = E[(size_t)j * NF + obs[t + 1]] * SCALE;
        const float4* x4 = (const float4*)xbuf[(t - 1) & 1];
        float y0 = 0.f, y1 = 0.f, y2 = 0.f, y3 = 0.f;
#pragma unroll
        for (int i = 0; i < NS / 4; ++i) {
            float4 xv = x4[i];
            y0 = fmaf(xv.x, a[4 * i + 0], y0);
            y1 = fmaf(xv.y, a[4 * i + 1], y1);
            y2 = fmaf(xv.z, a[4 * i + 2], y2);
            y3 = fmaf(xv.w, a[4 * i + 3], y3);
        }
        float y = ((y0 + y1) + (y2 + y3)) * se_cur;
        se_cur = se_nxt;
        out[(size_t)j * T_LEN + t] =
            LN2 * (__log2f(y) + Eacc - 15.0f * (float)(t + 1));
        float* wr = xbuf[t & 1];
        wr[j] = y;
        __syncthreads();
        if ((t & 1023) == 1023) {
            float v = wr[j];
#pragma unroll
            for (int d = 1; d < 64; d <<= 1) v = fmaxf(v, __shfl_xor(v, d, 64));
            if ((j & 63) == 0) red[j >> 6] = v;
            __syncthreads();
            float m = fmaxf(fmaxf(red[0], red[1]), fmaxf(red[2], red[3]));
            int k = ilogbf(m);
            wr[j] = ldexpf(wr[j], -k);
            Eacc += (float)k;
            __syncthreads();
        }
    }
}

extern "C" void kernel_launch(void* const* d_in, const int* in_sizes, int n_in,
                              void* d_out, int out_size, void* d_ws, size_t ws_size,
                              hipStream_t stream) {
    const float* start = (const float*)d_in[0];
    const float* A     = (const float*)d_in[1];
    const float* E     = (const float*)d_in[2];
    const int*   obs   = (const int*)d_in[3];
    float* out = (float*)d_out;

    char* ws = (char*)d_ws;
    const size_t zb_bytes  = (size_t)T_LEN * NS * sizeof(float);      // 8 MB
    const size_t se_bytes  = (size_t)T_LEN * NS * sizeof(float);      // 8 MB
    const size_t asw_bytes = (size_t)128 * 64 * 8 * sizeof(short);    // 128 KB

    float* z     = (float*)ws;
    float* SE    = (float*)(ws + zb_bytes);
    short* Aswz  = (short*)(ws + zb_bytes + se_bytes);
    float* Pb    = (float*)(ws + zb_bytes + se_bytes + asw_bytes);
    float* Qb    = Pb + C_CH;
    float* Dfull = Qb + C_CH;

    const size_t need = zb_bytes + se_bytes + asw_bytes +
                        (2 * C_CH + T_LEN) * sizeof(float);

    if (ws_size >= need) {
        prep<<<T_LEN + 128, 256, 0, stream>>>(E, obs, A, SE, Aswz);
        hmm_chains<<<NBLK, 1024, 0, stream>>>(start, SE, Aswz, z, Pb, Qb);
        hmm_stitch<<<1, 1024, 0, stream>>>(Pb, Qb, Dfull);
        hmm_finalize<<<dim3(T_LEN / 64, NS / 64), 256, 0, stream>>>(z, Dfull, out);
    } else {
        hmm_forward_seq<<<1, NS, 0, stream>>>(start, A, E, obs, out);
    }
}